// Round 11
// baseline (58.961 us; speedup 1.0000x reference)
//
#include <hip/hip_runtime.h>

#define NN   30000
#define NCTX 32
#define FIN  256
#define HID  128
#define HTBL 3840000   // bytes per half-table (N*64 f16)

typedef short short8 __attribute__((ext_vector_type(8)));
typedef float f32x4  __attribute__((ext_vector_type(4)));
typedef _Float16 half2v __attribute__((ext_vector_type(2)));

#define SEL_LO 0x01000504u
#define SEL_HI 0x03020706u

__device__ __forceinline__ unsigned short f2b(float x) {   // RTNE bf16
    union { float f; unsigned u; } v; v.f = x;
    unsigned r = v.u + 0x7FFFu + ((v.u >> 16) & 1u);
    return (unsigned short)(r >> 16);
}
__device__ __forceinline__ unsigned short f2b_trunc(float x) {
    union { float f; unsigned u; } v; v.f = x;
    return (unsigned short)(v.u >> 16);
}
__device__ __forceinline__ float b2f(unsigned short u) {
    union { unsigned u; float f; } v; v.u = ((unsigned)u) << 16;
    return v.f;
}
__device__ __forceinline__ unsigned short f2h(float x) {   // f32 -> f16 RTNE bits
    const _Float16 h = (_Float16)x;
    return __builtin_bit_cast(unsigned short, h);
}
__device__ __forceinline__ float dot2(unsigned vp, unsigned wp, float acc) {
    return __builtin_amdgcn_fdot2(__builtin_bit_cast(half2v, vp),
                                  __builtin_bit_cast(half2v, wp), acc, false);
}

// Blocks 0-63: pack W_j into MFMA B-fragment order (split bf16 hi/lo).
// Blocks 64-127: vi[f] = Wi[f,:].aw  (quarter-wave per feature, coalesced).
__global__ __launch_bounds__(64) void k_pack(const float* __restrict__ Wj,
                                             const float* __restrict__ Wi,
                                             const float* __restrict__ aw,
                                             short8* __restrict__ whi,
                                             short8* __restrict__ wlo,
                                             float* __restrict__ vi) {
    const int b = blockIdx.x;
    const int l = threadIdx.x;
    if (b >= 64) {
        const int fi = l >> 4;
        const int q  = l & 15;
        const int f  = (b - 64) * 4 + fi;
        const float4 w0 = *(const float4*)(Wi + (long)f * HID + q * 8);
        const float4 w1 = *(const float4*)(Wi + (long)f * HID + q * 8 + 4);
        const float4 a0 = *(const float4*)(aw + q * 8);
        const float4 a1 = *(const float4*)(aw + q * 8 + 4);
        float s = w0.x * a0.x + w0.y * a0.y + w0.z * a0.z + w0.w * a0.w
                + w1.x * a1.x + w1.y * a1.y + w1.z * a1.z + w1.w * a1.w;
        s += __shfl_xor(s, 1); s += __shfl_xor(s, 2);
        s += __shfl_xor(s, 4); s += __shfl_xor(s, 8);
        if (q == 0) vi[f] = s;
        return;
    }
    const int s = b >> 3, t = b & 7;
    const int kbase = s * 32 + (l >> 4) * 8;
    const int c = t * 16 + (l & 15);
    short8 hi, lo;
    #pragma unroll
    for (int j = 0; j < 8; ++j) {
        const float w = Wj[(long)(kbase + j) * HID + c];
        const unsigned short h = f2b_trunc(w);
        hi[j] = (short)h;
        lo[j] = (short)f2b(w - b2f(h));
    }
    whi[b * 64 + l] = hi;
    wlo[b * 64 + l] = lo;
}

// Fused: Wh = h_i @ W_j (MFMA, split-bf16), si = h_i.vi + ab, sj = Wh.a_w[128:]
// Table stored f16 as two column-half tables (cols 0-63 / 64-127).
__global__ __launch_bounds__(256) void k_gemm(const float* __restrict__ hin,
                                              const short8* __restrict__ whi,
                                              const short8* __restrict__ wlo,
                                              const float* __restrict__ vi,
                                              const float* __restrict__ aw,
                                              const float* __restrict__ ab,
                                              unsigned short* __restrict__ Wh0,
                                              unsigned short* __restrict__ Wh1,
                                              float* __restrict__ sib,
                                              float* __restrict__ sjv) {
    const int tid  = threadIdx.x;
    const int l    = tid & 63;
    const int wave = blockIdx.x * 4 + (tid >> 6);
    if (wave >= NN / 16) return;
    const long rowbase = (long)wave * 16;
    const int r  = l & 15;
    const int kg = l >> 4;

    const float* hrow = hin + (rowbase + r) * FIN + kg * 8;
    const float* vip  = vi + kg * 8;

    f32x4 acc[8];
    #pragma unroll
    for (int t = 0; t < 8; ++t) acc[t] = (f32x4){0.f, 0.f, 0.f, 0.f};
    float si = 0.f;

    #pragma unroll
    for (int s = 0; s < 8; ++s) {
        short8 BH[8], BL[8];
        #pragma unroll
        for (int t = 0; t < 8; ++t) {
            BH[t] = whi[(s * 8 + t) * 64 + l];
            BL[t] = wlo[(s * 8 + t) * 64 + l];
        }
        const float4 ha = *(const float4*)(hrow + s * 32);
        const float4 hb = *(const float4*)(hrow + s * 32 + 4);
        const float4 va = *(const float4*)(vip + s * 32);
        const float4 vb = *(const float4*)(vip + s * 32 + 4);
        const float hv[8] = {ha.x, ha.y, ha.z, ha.w, hb.x, hb.y, hb.z, hb.w};
        const float vv[8] = {va.x, va.y, va.z, va.w, vb.x, vb.y, vb.z, vb.w};
        short8 ahi, alo;
        #pragma unroll
        for (int j = 0; j < 8; ++j) {
            si += hv[j] * vv[j];
            const unsigned short hb16 = f2b_trunc(hv[j]);
            ahi[j] = (short)hb16;
            alo[j] = (short)f2b(hv[j] - b2f(hb16));
        }
        #pragma unroll
        for (int t = 0; t < 8; ++t) {
            acc[t] = __builtin_amdgcn_mfma_f32_16x16x32_bf16(ahi, BH[t], acc[t], 0, 0, 0);
            acc[t] = __builtin_amdgcn_mfma_f32_16x16x32_bf16(alo, BH[t], acc[t], 0, 0, 0);
            acc[t] = __builtin_amdgcn_mfma_f32_16x16x32_bf16(ahi, BL[t], acc[t], 0, 0, 0);
        }
    }

    si += __shfl_xor(si, 16);
    si += __shfl_xor(si, 32);
    if (l < 16) sib[rowbase + l] = si + ab[0];

    float aw2v[8];
    #pragma unroll
    for (int t = 0; t < 8; ++t) aw2v[t] = aw[HID + t * 16 + r];
    #pragma unroll
    for (int j = 0; j < 4; ++j) {
        float p = 0.f;
        #pragma unroll
        for (int t = 0; t < 8; ++t) p += acc[t][j] * aw2v[t];
        p += __shfl_xor(p, 1); p += __shfl_xor(p, 2);
        p += __shfl_xor(p, 4); p += __shfl_xor(p, 8);
        if (r == 0) sjv[rowbase + kg * 4 + j] = p;
    }

    #pragma unroll
    for (int j = 0; j < 4; ++j) {
        const long rr = rowbase + kg * 4 + j;
        #pragma unroll
        for (int t = 0; t < 4; ++t)
            Wh0[rr * 64 + t * 16 + r] = f2h(acc[t][j]);
        #pragma unroll
        for (int t = 4; t < 8; ++t)
            Wh1[rr * 64 + (t - 4) * 16 + r] = f2h(acc[t][j]);
    }
}

// One column-half pass. Prewarm: blocks sliced by (bid>>3) stream the whole
// 3.84MB half-table into each XCD's L2 (round-robin dispatch => blocks with
// the same bid&7 land on the same XCD). Then: softmax (recomputed per pass)
// + gather from the warm table with the f16 dot2 core. 2 nodes per wave.
__global__ __launch_bounds__(256) void k_attn_half(const int* __restrict__ ctx,
                                                   const unsigned short* __restrict__ Whp,
                                                   const float* __restrict__ sib,
                                                   const float* __restrict__ sjv,
                                                   float* __restrict__ out,
                                                   int p) {
    const int tid  = threadIdx.x;
    const int lane = tid & 63;

    // ---- prewarm: 8KB per block, sliced per-XCD ----
    {
        const char* wb = (const char*)Whp;
        const long o1 = (long)(blockIdx.x >> 3) * 8192 + tid * 16;
        const long o2 = o1 + 4096;
        unsigned k1 = 0, k2 = 0;
        if (o1 < HTBL) k1 = ((const uint4*)(wb + o1))->x;
        if (o2 < HTBL) k2 = ((const uint4*)(wb + o2))->x;
        asm volatile("" :: "v"(k1), "v"(k2));
    }

    const int wid  = tid >> 6;
    const long nb  = (long)blockIdx.x * 8 + wid * 2;
    const int h    = lane >> 5;          // which of the 2 nodes
    const long n   = nb + h;
    const int c    = lane & 31;

    const int idx = ctx[n * NCTX + c];
    const int icl = (idx >= 0) ? idx : 0;
    float s;
    if (idx >= 0) {
        s = sib[n] + sjv[icl];
        s = (s >= 0.f) ? s : 0.2f * s;
    } else {
        s = -9e15f;
    }
    float mx = s;
    #pragma unroll
    for (int m = 16; m >= 1; m >>= 1) mx = fmaxf(mx, __shfl_xor(mx, m));
    const float e = __expf(s - mx);
    float sum = e;
    #pragma unroll
    for (int m = 16; m >= 1; m >>= 1) sum += __shfl_xor(sum, m);
    const float at = (idx >= 0) ? e / sum : 0.f;

    const int r  = (lane >> 3) & 3;   // row-slot within node
    const int cl = lane & 7;          // 16-B chunk within the 128-B half-row
    const char* base = (const char*)Whp;

    float a[8] = {0.f,0.f,0.f,0.f,0.f,0.f,0.f,0.f};
    #pragma unroll
    for (int pp = 0; pp < 4; ++pp) {
        const int srcA = (lane & 32) | (pp * 8 + r);
        const int srcB = (lane & 32) | (pp * 8 + 4 + r);
        const float wA = __shfl(at,  srcA);
        const int   iA = __shfl(icl, srcA);
        const float wB = __shfl(at,  srcB);
        const int   iB = __shfl(icl, srcB);
        const uint4 uA = *(const uint4*)(base + (((unsigned)iA << 7) | (cl << 4)));
        const uint4 uB = *(const uint4*)(base + (((unsigned)iB << 7) | (cl << 4)));
        const unsigned hA = (unsigned)f2h(wA);
        const unsigned hB = (unsigned)f2h(wB);
        const unsigned wp = __builtin_amdgcn_perm(hA, hB, SEL_LO);
        a[0] = dot2(__builtin_amdgcn_perm(uA.x, uB.x, SEL_LO), wp, a[0]);
        a[1] = dot2(__builtin_amdgcn_perm(uA.x, uB.x, SEL_HI), wp, a[1]);
        a[2] = dot2(__builtin_amdgcn_perm(uA.y, uB.y, SEL_LO), wp, a[2]);
        a[3] = dot2(__builtin_amdgcn_perm(uA.y, uB.y, SEL_HI), wp, a[3]);
        a[4] = dot2(__builtin_amdgcn_perm(uA.z, uB.z, SEL_LO), wp, a[4]);
        a[5] = dot2(__builtin_amdgcn_perm(uA.z, uB.z, SEL_HI), wp, a[5]);
        a[6] = dot2(__builtin_amdgcn_perm(uA.w, uB.w, SEL_LO), wp, a[6]);
        a[7] = dot2(__builtin_amdgcn_perm(uA.w, uB.w, SEL_HI), wp, a[7]);
    }
    // reduce over row-slot r (lane bits 3,4)
    #pragma unroll
    for (int i = 0; i < 8; ++i) {
        a[i] += __shfl_xor(a[i], 8);
        a[i] += __shfl_xor(a[i], 16);
    }
    if (r == 0) {
        float4* op = (float4*)(out + n * HID + p * 64 + cl * 8);
        op[0] = (float4){a[0], a[1], a[2], a[3]};
        op[1] = (float4){a[4], a[5], a[6], a[7]};
    }
}

extern "C" void kernel_launch(void* const* d_in, const int* in_sizes, int n_in,
                              void* d_out, int out_size, void* d_ws, size_t ws_size,
                              hipStream_t stream) {
    const float* h_i = (const float*)d_in[0];
    const int*   ctx = (const int*)d_in[1];
    const float* W_i = (const float*)d_in[2];
    const float* W_j = (const float*)d_in[3];
    const float* a_w = (const float*)d_in[4];
    const float* a_b = (const float*)d_in[5];
    float* out = (float*)d_out;

    char* ws = (char*)d_ws;
    unsigned short* Wh0 = (unsigned short*)ws;            // N*64 f16
    unsigned short* Wh1 = (unsigned short*)(ws + HTBL);   // N*64 f16
    float* sib = (float*)(ws + 7680000);                  // N f32
    float* sjv = (float*)(ws + 7800000);                  // N f32
    float* vi  = (float*)(ws + 7920000);                  // 256 f32
    short8* whi = (short8*)(ws + 7921024);                // 64 KB
    short8* wlo = (short8*)(ws + 7986560);                // 64 KB

    k_pack<<<128, 64, 0, stream>>>(W_j, W_i, a_w, whi, wlo, vi);
    k_gemm<<<(NN / 16 + 3) / 4, 256, 0, stream>>>(h_i, whi, wlo, vi, a_w, a_b,
                                                  Wh0, Wh1, sib, sjv);
    k_attn_half<<<NN / 8, 256, 0, stream>>>(ctx, Wh0, sib, sjv, out, 0);
    k_attn_half<<<NN / 8, 256, 0, stream>>>(ctx, Wh1, sib, sjv, out, 1);
}

// Round 12
// 47.779 us; speedup vs baseline: 1.2341x; 1.2341x over previous
//
#include <hip/hip_runtime.h>

#define NN   30000
#define NCTX 32
#define FIN  256
#define HID  128

typedef float f32x4  __attribute__((ext_vector_type(4)));
typedef _Float16 half8 __attribute__((ext_vector_type(8)));
typedef _Float16 half2v __attribute__((ext_vector_type(2)));

#define SEL_LO 0x01000504u
#define SEL_HI 0x03020706u

__device__ __forceinline__ unsigned short f2h(float x) {   // f32 -> f16 RTNE bits
    const _Float16 h = (_Float16)x;
    return __builtin_bit_cast(unsigned short, h);
}
__device__ __forceinline__ float dot2(unsigned vp, unsigned wp, float acc) {
    return __builtin_amdgcn_fdot2(__builtin_bit_cast(half2v, vp),
                                  __builtin_bit_cast(half2v, wp), acc, false);
}

// Blocks 0-63: pack W_j into f16 MFMA B-fragments.
// Blocks 64-127: vi[f] = Wi[f,:].aw  (quarter-wave per feature, coalesced).
__global__ __launch_bounds__(64) void k_pack(const float* __restrict__ Wj,
                                             const float* __restrict__ Wi,
                                             const float* __restrict__ aw,
                                             half8* __restrict__ whf,
                                             float* __restrict__ vi) {
    const int b = blockIdx.x;
    const int l = threadIdx.x;
    if (b >= 64) {
        const int fi = l >> 4;
        const int q  = l & 15;
        const int f  = (b - 64) * 4 + fi;
        const float4 w0 = *(const float4*)(Wi + (long)f * HID + q * 8);
        const float4 w1 = *(const float4*)(Wi + (long)f * HID + q * 8 + 4);
        const float4 a0 = *(const float4*)(aw + q * 8);
        const float4 a1 = *(const float4*)(aw + q * 8 + 4);
        float s = w0.x * a0.x + w0.y * a0.y + w0.z * a0.z + w0.w * a0.w
                + w1.x * a1.x + w1.y * a1.y + w1.z * a1.z + w1.w * a1.w;
        s += __shfl_xor(s, 1); s += __shfl_xor(s, 2);
        s += __shfl_xor(s, 4); s += __shfl_xor(s, 8);
        if (q == 0) vi[f] = s;
        return;
    }
    const int s = b >> 3, t = b & 7;
    const int kbase = s * 32 + (l >> 4) * 8;
    const int c = t * 16 + (l & 15);
    half8 w;
    #pragma unroll
    for (int j = 0; j < 8; ++j)
        w[j] = (_Float16)Wj[(long)(kbase + j) * HID + c];
    whf[b * 64 + l] = w;
}

// Fused: Wh = h_i @ W_j (single f16 MFMA), si = h_i.vi + ab, sj = Wh.a_w[128:]
// Table Wh stored f16 (256-B rows).
__global__ __launch_bounds__(256) void k_gemm(const float* __restrict__ hin,
                                              const half8* __restrict__ whf,
                                              const float* __restrict__ vi,
                                              const float* __restrict__ aw,
                                              const float* __restrict__ ab,
                                              unsigned short* __restrict__ Wh,
                                              float* __restrict__ sib,
                                              float* __restrict__ sjv) {
    const int tid  = threadIdx.x;
    const int l    = tid & 63;
    const int wave = blockIdx.x * 4 + (tid >> 6);
    if (wave >= NN / 16) return;
    const long rowbase = (long)wave * 16;
    const int r  = l & 15;
    const int kg = l >> 4;

    const float* hrow = hin + (rowbase + r) * FIN + kg * 8;
    const float* vip  = vi + kg * 8;

    f32x4 acc[8];
    #pragma unroll
    for (int t = 0; t < 8; ++t) acc[t] = (f32x4){0.f, 0.f, 0.f, 0.f};
    float si = 0.f;

    #pragma unroll
    for (int s = 0; s < 8; ++s) {
        half8 B[8];
        #pragma unroll
        for (int t = 0; t < 8; ++t) B[t] = whf[(s * 8 + t) * 64 + l];
        const float4 ha = *(const float4*)(hrow + s * 32);
        const float4 hb = *(const float4*)(hrow + s * 32 + 4);
        const float4 va = *(const float4*)(vip + s * 32);
        const float4 vb = *(const float4*)(vip + s * 32 + 4);
        si += ha.x * va.x + ha.y * va.y + ha.z * va.z + ha.w * va.w
            + hb.x * vb.x + hb.y * vb.y + hb.z * vb.z + hb.w * vb.w;
        half8 a;
        a[0] = (_Float16)ha.x; a[1] = (_Float16)ha.y;
        a[2] = (_Float16)ha.z; a[3] = (_Float16)ha.w;
        a[4] = (_Float16)hb.x; a[5] = (_Float16)hb.y;
        a[6] = (_Float16)hb.z; a[7] = (_Float16)hb.w;
        #pragma unroll
        for (int t = 0; t < 8; ++t)
            acc[t] = __builtin_amdgcn_mfma_f32_16x16x32_f16(a, B[t], acc[t], 0, 0, 0);
    }

    si += __shfl_xor(si, 16);
    si += __shfl_xor(si, 32);
    if (l < 16) sib[rowbase + l] = si + ab[0];

    float aw2v[8];
    #pragma unroll
    for (int t = 0; t < 8; ++t) aw2v[t] = aw[HID + t * 16 + r];
    #pragma unroll
    for (int j = 0; j < 4; ++j) {
        float p = 0.f;
        #pragma unroll
        for (int t = 0; t < 8; ++t) p += acc[t][j] * aw2v[t];
        p += __shfl_xor(p, 1); p += __shfl_xor(p, 2);
        p += __shfl_xor(p, 4); p += __shfl_xor(p, 8);
        if (r == 0) sjv[rowbase + kg * 4 + j] = p;
    }

    #pragma unroll
    for (int j = 0; j < 4; ++j) {
        const long rr = rowbase + kg * 4 + j;
        #pragma unroll
        for (int t = 0; t < 8; ++t)
            Wh[rr * HID + t * 16 + r] = f2h(acc[t][j]);
    }
}

// per-node softmax + gather-aggregate, f16 table + v_dot2_f32_f16 core.
// Quarter-wave per row; contexts paired: 2 v_perm + 2 dot2 per word-pair.
__global__ __launch_bounds__(256) void k_attn(const int* __restrict__ ctx,
                                              const unsigned short* __restrict__ Wh,
                                              const float* __restrict__ sib,
                                              const float* __restrict__ sjv,
                                              float* __restrict__ out) {
    const int lane = threadIdx.x & 63;
    const long n = (long)blockIdx.x * 4 + (threadIdx.x >> 6);
    const int c = lane & 31;
    const int idx = ctx[n * NCTX + c];
    const int icl = (idx >= 0) ? idx : 0;
    float s;
    if (idx >= 0) {
        s = sib[n] + sjv[icl];
        s = (s >= 0.f) ? s : 0.2f * s;
    } else {
        s = -9e15f;
    }
    float mx = s;
    #pragma unroll
    for (int m = 16; m >= 1; m >>= 1) mx = fmaxf(mx, __shfl_xor(mx, m));
    const float e = __expf(s - mx);
    float sum = e;
    #pragma unroll
    for (int m = 16; m >= 1; m >>= 1) sum += __shfl_xor(sum, m);
    const float at = (idx >= 0) ? e / sum : 0.f;

    const int q  = lane >> 4;               // row-quarter
    const unsigned coff = (lane & 15) * 16; // byte offset of 16-B chunk in 256-B row
    const char* base = (const char*)Wh;

    float a[8] = {0.f,0.f,0.f,0.f,0.f,0.f,0.f,0.f};
    #pragma unroll
    for (int p = 0; p < 4; ++p) {
        const float wA = __shfl(at,  p * 8 + q);
        const int   iA = __shfl(icl, p * 8 + q);
        const float wB = __shfl(at,  p * 8 + 4 + q);
        const int   iB = __shfl(icl, p * 8 + 4 + q);
        const uint4 uA = *(const uint4*)(base + (((unsigned)iA << 8) | coff));
        const uint4 uB = *(const uint4*)(base + (((unsigned)iB << 8) | coff));
        const unsigned hA = (unsigned)f2h(wA);
        const unsigned hB = (unsigned)f2h(wB);
        const unsigned wp = __builtin_amdgcn_perm(hA, hB, SEL_LO);
        a[0] = dot2(__builtin_amdgcn_perm(uA.x, uB.x, SEL_LO), wp, a[0]);
        a[1] = dot2(__builtin_amdgcn_perm(uA.x, uB.x, SEL_HI), wp, a[1]);
        a[2] = dot2(__builtin_amdgcn_perm(uA.y, uB.y, SEL_LO), wp, a[2]);
        a[3] = dot2(__builtin_amdgcn_perm(uA.y, uB.y, SEL_HI), wp, a[3]);
        a[4] = dot2(__builtin_amdgcn_perm(uA.z, uB.z, SEL_LO), wp, a[4]);
        a[5] = dot2(__builtin_amdgcn_perm(uA.z, uB.z, SEL_HI), wp, a[5]);
        a[6] = dot2(__builtin_amdgcn_perm(uA.w, uB.w, SEL_LO), wp, a[6]);
        a[7] = dot2(__builtin_amdgcn_perm(uA.w, uB.w, SEL_HI), wp, a[7]);
    }
    #pragma unroll
    for (int i = 0; i < 8; ++i) {
        a[i] += __shfl_xor(a[i], 16);
        a[i] += __shfl_xor(a[i], 32);
    }
    if (lane < 16) {
        float4* op = (float4*)(out + n * HID + (coff >> 2) * 2);
        op[0] = (float4){a[0], a[1], a[2], a[3]};
        op[1] = (float4){a[4], a[5], a[6], a[7]};
    }
}

extern "C" void kernel_launch(void* const* d_in, const int* in_sizes, int n_in,
                              void* d_out, int out_size, void* d_ws, size_t ws_size,
                              hipStream_t stream) {
    const float* h_i = (const float*)d_in[0];
    const int*   ctx = (const int*)d_in[1];
    const float* W_i = (const float*)d_in[2];
    const float* W_j = (const float*)d_in[3];
    const float* a_w = (const float*)d_in[4];
    const float* a_b = (const float*)d_in[5];
    float* out = (float*)d_out;

    char* ws = (char*)d_ws;
    unsigned short* Wh = (unsigned short*)ws;             // N*H f16 = 7,680,000 B
    float* sib = (float*)(ws + 7680000);                  // N f32
    float* sjv = (float*)(ws + 7800000);                  // N f32
    float* vi  = (float*)(ws + 7920000);                  // 256 f32
    half8* whf = (half8*)(ws + 7921024);                  // 64 KB f16 fragments

    k_pack<<<128, 64, 0, stream>>>(W_j, W_i, a_w, whf, vi);
    k_gemm<<<(NN / 16 + 3) / 4, 256, 0, stream>>>(h_i, whf, vi, a_w, a_b, Wh, sib, sjv);
    k_attn<<<NN / 4, 256, 0, stream>>>(ctx, Wh, sib, sjv, out);
}